// Round 3
// baseline (522.194 us; speedup 1.0000x reference)
//
#include <hip/hip_runtime.h>
#include <hip/hip_bf16.h>

// GraphSage: 3x SAGEConv(mean) + linear head. fp32 end-to-end.
// NOTE: harness delivers integer inputs as int32 — edge_index is const int*
// with layout [src[0..NE), dst[0..NE)]. (Round 1/2 aborts were an int64
// misread of this buffer: 2x OOB reads + garbage atomic indices.)
// Workspace (~55 MB): cnt | cursor | partial | perm | sbuf[N,128] | hA[N,128]
// CSR built once per call: degree count -> exclusive scan -> atomic-slot scatter.
// Per layer: wave-per-node mean aggregate (no atomics) -> fused GEMM
//   out = relu([mean|h] @ [Wl|Wr]^T + bl), in-place over h (block row ranges
//   disjoint; all reads of the block's rows precede its writes).

constexpr int NN = 50000;
constexpr int NE = 800000;
constexpr int NCH = (NN + 255) / 256;   // 196 scan chunks

__global__ void k_zero_int(int* __restrict__ a, int n) {
    int i = blockIdx.x * blockDim.x + threadIdx.x;
    if (i < n) a[i] = 0;
}

__global__ void k_count(const int* __restrict__ ei, int* __restrict__ cnt) {
    int e = blockIdx.x * blockDim.x + threadIdx.x;
    if (e < NE) {
        int d = ei[NE + e];
        atomicAdd(&cnt[d], 1);
    }
}

__global__ void k_chunk_sums(const int* __restrict__ cnt, int* __restrict__ partial) {
    __shared__ int ws[4];
    int i = blockIdx.x * 256 + threadIdx.x;
    int v = (i < NN) ? cnt[i] : 0;
    for (int o = 32; o > 0; o >>= 1) v += __shfl_down(v, o);
    int lane = threadIdx.x & 63, wave = threadIdx.x >> 6;
    if (lane == 0) ws[wave] = v;
    __syncthreads();
    if (threadIdx.x == 0) partial[blockIdx.x] = ws[0] + ws[1] + ws[2] + ws[3];
}

__global__ void k_scan_partials(int* __restrict__ partial, int n) {
    __shared__ int ws[4];
    int t = threadIdx.x;
    int orig = (t < n) ? partial[t] : 0;
    int v = orig;
    int lane = t & 63, wave = t >> 6;
    for (int o = 1; o < 64; o <<= 1) { int u = __shfl_up(v, o); if (lane >= o) v += u; }
    if (lane == 63) ws[wave] = v;
    __syncthreads();
    int off = 0;
    for (int w = 0; w < 4; ++w) if (w < wave) off += ws[w];
    if (t < n) partial[t] = v + off - orig;   // exclusive
}

// exclusive prefix sum of cnt -> cursor
__global__ void k_scan_chunks(const int* __restrict__ cnt, const int* __restrict__ partial,
                              int* __restrict__ cursor) {
    __shared__ int ws[4];
    int i = blockIdx.x * 256 + threadIdx.x;
    int orig = (i < NN) ? cnt[i] : 0;
    int v = orig;
    int lane = threadIdx.x & 63, wave = threadIdx.x >> 6;
    for (int o = 1; o < 64; o <<= 1) { int u = __shfl_up(v, o); if (lane >= o) v += u; }
    if (lane == 63) ws[wave] = v;
    __syncthreads();
    int off = partial[blockIdx.x];
    for (int w = 0; w < 4; ++w) if (w < wave) off += ws[w];
    if (i < NN) cursor[i] = v - orig + off;
}

// cursor[d] = node's next free CSR slot; after this kernel cursor[d] == row_end(d).
__global__ void k_scatter(const int* __restrict__ ei, int* __restrict__ cursor,
                          int* __restrict__ perm) {
    int e = blockIdx.x * blockDim.x + threadIdx.x;
    if (e < NE) {
        int s = ei[e];
        int d = ei[NE + e];
        int pos = atomicAdd(&cursor[d], 1);
        perm[pos] = s;
    }
}

// one wave per node; lane l holds cols [2l, 2l+1] as float2
__global__ __launch_bounds__(256) void k_aggregate(const float* __restrict__ h,
        const int* __restrict__ cursor, const int* __restrict__ cnt,
        const int* __restrict__ perm, float* __restrict__ outbuf) {
    int wave = __builtin_amdgcn_readfirstlane(threadIdx.x >> 6);
    int lane = threadIdx.x & 63;
    int node = blockIdx.x * 4 + wave;
    if (node >= NN) return;
    int deg = cnt[node];
    int start = cursor[node] - deg;
    const float2* hp = (const float2*)h;   // row stride = 64 float2
    float2 acc = make_float2(0.f, 0.f);
    int j = 0;
    for (; j + 4 <= deg; j += 4) {
        int s0 = perm[start + j + 0];
        int s1 = perm[start + j + 1];
        int s2 = perm[start + j + 2];
        int s3 = perm[start + j + 3];
        float2 v0 = hp[(size_t)s0 * 64 + lane];
        float2 v1 = hp[(size_t)s1 * 64 + lane];
        float2 v2 = hp[(size_t)s2 * 64 + lane];
        float2 v3 = hp[(size_t)s3 * 64 + lane];
        acc.x += (v0.x + v1.x) + (v2.x + v3.x);
        acc.y += (v0.y + v1.y) + (v2.y + v3.y);
    }
    for (; j < deg; ++j) {
        int s = perm[start + j];
        float2 v = hp[(size_t)s * 64 + lane];
        acc.x += v.x;
        acc.y += v.y;
    }
    float inv = 1.0f / (float)(deg > 1 ? deg : 1);
    ((float2*)outbuf)[(size_t)node * 64 + lane] = make_float2(acc.x * inv, acc.y * inv);
}

// out[n][c] = relu( bl[c] + sum_k A0[n][k]*Wl[c][k] + sum_k A1[n][k]*Wr[c][k] )
// block: 64 nodes x 128 cols; 256 threads; thread tile 8 nodes x 4 cols; K chunks of 32.
__global__ __launch_bounds__(256) void k_sage_gemm(const float* __restrict__ A0,
        const float* __restrict__ A1, const float* __restrict__ Wl,
        const float* __restrict__ Wr, const float* __restrict__ bias,
        float* __restrict__ out) {
    __shared__ float lA[32][68];    // [kk][node]
    __shared__ float lB[32][132];   // [kk][col]
    int t = threadIdx.x;
    int n0 = blockIdx.x * 64;
    int cg = t & 31;    // cols 4cg..4cg+3
    int ng = t >> 5;    // nodes 8ng..8ng+7
    float acc[8][4] = {};
    for (int kc = 0; kc < 8; ++kc) {
        int k0 = (kc & 3) * 32;
        const float* __restrict__ A = (kc < 4) ? A0 : A1;
        const float* __restrict__ W = (kc < 4) ? Wl : Wr;
        __syncthreads();
        // stage A-tile: 64 nodes x 32 k
        for (int i = t; i < 512; i += 256) {
            int nl = i >> 3;          // node 0..63
            int kq = i & 7;           // k quad 0..7
            int n = n0 + nl;
            float4 v = (n < NN) ? *(const float4*)&A[(size_t)n * 128 + k0 + 4 * kq]
                                : make_float4(0.f, 0.f, 0.f, 0.f);
            lA[4 * kq + 0][nl] = v.x;
            lA[4 * kq + 1][nl] = v.y;
            lA[4 * kq + 2][nl] = v.z;
            lA[4 * kq + 3][nl] = v.w;
        }
        // stage B-tile: 128 cols x 32 k
        for (int i = t; i < 1024; i += 256) {
            int c = i >> 3;
            int kq = i & 7;
            float4 v = *(const float4*)&W[c * 128 + k0 + 4 * kq];
            lB[4 * kq + 0][c] = v.x;
            lB[4 * kq + 1][c] = v.y;
            lB[4 * kq + 2][c] = v.z;
            lB[4 * kq + 3][c] = v.w;
        }
        __syncthreads();
#pragma unroll
        for (int kk = 0; kk < 32; ++kk) {
            float4 b = *(const float4*)&lB[kk][cg * 4];
            float4 a0 = *(const float4*)&lA[kk][ng * 8];
            float4 a1 = *(const float4*)&lA[kk][ng * 8 + 4];
            float av[8] = {a0.x, a0.y, a0.z, a0.w, a1.x, a1.y, a1.z, a1.w};
#pragma unroll
            for (int i = 0; i < 8; ++i) {
                acc[i][0] += av[i] * b.x;
                acc[i][1] += av[i] * b.y;
                acc[i][2] += av[i] * b.z;
                acc[i][3] += av[i] * b.w;
            }
        }
    }
    float4 bb = *(const float4*)&bias[cg * 4];
#pragma unroll
    for (int i = 0; i < 8; ++i) {
        int n = n0 + ng * 8 + i;
        if (n < NN) {
            float4 r;
            r.x = fmaxf(acc[i][0] + bb.x, 0.f);
            r.y = fmaxf(acc[i][1] + bb.y, 0.f);
            r.z = fmaxf(acc[i][2] + bb.z, 0.f);
            r.w = fmaxf(acc[i][3] + bb.w, 0.f);
            *(float4*)&out[(size_t)n * 128 + cg * 4] = r;
        }
    }
}

__global__ __launch_bounds__(256) void k_final(const float* __restrict__ h,
        const float* __restrict__ Wf, const float* __restrict__ bf,
        float* __restrict__ out) {
    int wave = __builtin_amdgcn_readfirstlane(threadIdx.x >> 6);
    int lane = threadIdx.x & 63;
    int node = blockIdx.x * 4 + wave;
    if (node >= NN) return;
    float2 w = ((const float2*)Wf)[lane];
    float2 v = ((const float2*)h)[(size_t)node * 64 + lane];
    float s = v.x * w.x + v.y * w.y;
    for (int o = 32; o > 0; o >>= 1) s += __shfl_down(s, o);
    if (lane == 0) out[node] = s + bf[0];
}

extern "C" void kernel_launch(void* const* d_in, const int* in_sizes, int n_in,
                              void* d_out, int out_size, void* d_ws, size_t ws_size,
                              hipStream_t stream) {
    const float* x   = (const float*)d_in[0];
    const int*   ei  = (const int*)d_in[1];     // int32! [2, NE] flattened
    const float* Wl0 = (const float*)d_in[2];
    const float* bl0 = (const float*)d_in[3];
    const float* Wr0 = (const float*)d_in[4];
    const float* Wl1 = (const float*)d_in[5];
    const float* bl1 = (const float*)d_in[6];
    const float* Wr1 = (const float*)d_in[7];
    const float* Wl2 = (const float*)d_in[8];
    const float* bl2 = (const float*)d_in[9];
    const float* Wr2 = (const float*)d_in[10];
    const float* Wf  = (const float*)d_in[11];
    const float* bf  = (const float*)d_in[12];
    float* out = (float*)d_out;

    char* p = (char*)d_ws;
    auto alloc = [&](size_t n) { void* r = (void*)p; p += (n + 255) & ~(size_t)255; return r; };
    int*   cnt     = (int*)alloc((size_t)NN * 4);
    int*   cursor  = (int*)alloc((size_t)NN * 4);
    int*   partial = (int*)alloc(256 * 4);
    int*   perm    = (int*)alloc((size_t)NE * 4);
    float* sbuf    = (float*)alloc((size_t)NN * 128 * 4);
    float* hA      = (float*)alloc((size_t)NN * 128 * 4);

    dim3 b256(256);
    // CSR build
    k_zero_int<<<dim3((NN + 255) / 256), b256, 0, stream>>>(cnt, NN);
    k_count<<<dim3((NE + 255) / 256), b256, 0, stream>>>(ei, cnt);
    k_chunk_sums<<<dim3(NCH), b256, 0, stream>>>(cnt, partial);
    k_scan_partials<<<dim3(1), b256, 0, stream>>>(partial, NCH);
    k_scan_chunks<<<dim3(NCH), b256, 0, stream>>>(cnt, partial, cursor);
    k_scatter<<<dim3((NE + 255) / 256), b256, 0, stream>>>(ei, cursor, perm);

    dim3 gAgg((NN + 3) / 4);
    dim3 gGemm((NN + 63) / 64);

    // layer 0: h_in = x (read-only input), out -> hA
    k_aggregate<<<gAgg, b256, 0, stream>>>(x, cursor, cnt, perm, sbuf);
    k_sage_gemm<<<gGemm, b256, 0, stream>>>(sbuf, x, Wl0, Wr0, bl0, hA);
    // layer 1: in-place hA -> hA
    k_aggregate<<<gAgg, b256, 0, stream>>>(hA, cursor, cnt, perm, sbuf);
    k_sage_gemm<<<gGemm, b256, 0, stream>>>(sbuf, hA, Wl1, Wr1, bl1, hA);
    // layer 2: in-place hA -> hA
    k_aggregate<<<gAgg, b256, 0, stream>>>(hA, cursor, cnt, perm, sbuf);
    k_sage_gemm<<<gGemm, b256, 0, stream>>>(sbuf, hA, Wl2, Wr2, bl2, hA);
    // head
    k_final<<<gAgg, b256, 0, stream>>>(hA, Wf, bf, out);
}